// Round 1
// baseline (590.020 us; speedup 1.0000x reference)
//
#include <hip/hip_runtime.h>
#include <hip/hip_bf16.h>
#include <stdint.h>

// BilinearDiscriminator: out = sigmoid((x*mask_x) @ W^T @ (y*mask_y)^T)
// fp32 precision recovered via bf16 hi/lo split (3 MFMA passes: hh + hl + lh).

typedef __bf16 bf16_t;
typedef bf16_t bf16x8 __attribute__((ext_vector_type(8)));
typedef bf16_t bf16x4 __attribute__((ext_vector_type(4)));
typedef float f32x4 __attribute__((ext_vector_type(4)));

#define N_ROWS 8192
#define M_ROWS 8192
#define DDIM 512

#define BM 128
#define BN 128
#define BK 32

// async global->LDS, 16B per lane. LDS dest must be wave_base + lane*16.
__device__ __forceinline__ void async_cp16(const bf16_t* g, bf16_t* l) {
    __builtin_amdgcn_global_load_lds(
        (const __attribute__((address_space(1))) unsigned int*)(uintptr_t)g,
        (__attribute__((address_space(3))) unsigned int*)(uint32_t)(uintptr_t)l,
        16, 0, 0);
}

// Fused dropout-multiply + fp32 -> (bf16 hi, bf16 lo) split.
// mask == nullptr means no dropout (used for W).
__global__ __launch_bounds__(256) void prep_split(
    const float* __restrict__ v, const float* __restrict__ mask,
    bf16_t* __restrict__ hi, bf16_t* __restrict__ lo, int total4) {
    int idx = blockIdx.x * blockDim.x + threadIdx.x;
    if (idx >= total4) return;
    float4 xv = ((const float4*)v)[idx];
    if (mask) {
        float4 mv = ((const float4*)mask)[idx];
        xv.x *= mv.x; xv.y *= mv.y; xv.z *= mv.z; xv.w *= mv.w;
    }
    float vals[4] = {xv.x, xv.y, xv.z, xv.w};
    bf16x4 h, l;
#pragma unroll
    for (int i = 0; i < 4; ++i) {
        bf16_t hh = (bf16_t)vals[i];
        h[i] = hh;
        l[i] = (bf16_t)(vals[i] - (float)hh);
    }
    *(bf16x4*)(hi + (size_t)idx * 4) = h;
    *(bf16x4*)(lo + (size_t)idx * 4) = l;
}

// C[i,j] = sum_k A[i,k]*B[j,k], computed as Ah*Bh + Ah*Bl + Al*Bh over 3 segments.
// A: rows x 512 (hi/lo), B: cols x 512 (hi/lo). Tiles: 128x128, BK=32.
// EPI==0: split fp32 result into Chi/Clo (bf16), ldc = DDIM.
// EPI==1: sigmoid -> Cf (fp32), ldc = M_ROWS.
template <int EPI>
__global__ __launch_bounds__(256) void gemm_bt(
    const bf16_t* __restrict__ Ahi, const bf16_t* __restrict__ Alo,
    const bf16_t* __restrict__ Bhi, const bf16_t* __restrict__ Blo,
    float* __restrict__ Cf,
    bf16_t* __restrict__ Chi, bf16_t* __restrict__ Clo,
    int ldc) {
    __shared__ __align__(16) bf16_t As[BM * BK];
    __shared__ __align__(16) bf16_t Bs[BN * BK];

    const int tid = threadIdx.x;
    const int lane = tid & 63;
    const int wave = tid >> 6;
    const int wm = (wave & 1) * 64;   // wave row offset in tile
    const int wn = (wave >> 1) * 64;  // wave col offset in tile
    const int bm = blockIdx.y;
    const int bn = blockIdx.x;

    // staging: thread t covers (row = t/4, col = (t%4)*8), 16B each; LDS offset = t*16B
    const int srow = tid >> 2;
    const int scol = (tid & 3) * 8;

    // MFMA A/B fragment addressing: row/col = lane&15, k = (lane>>4)*8 + j
    const int m0 = lane & 15;
    const int kq = (lane >> 4) * 8;

    f32x4 acc[4][4];
#pragma unroll
    for (int i = 0; i < 4; ++i)
#pragma unroll
        for (int j = 0; j < 4; ++j)
            acc[i][j] = (f32x4){0.f, 0.f, 0.f, 0.f};

    const bf16_t* Aseg[3] = {Ahi, Ahi, Alo};
    const bf16_t* Bseg[3] = {Bhi, Blo, Bhi};

    bf16_t* Al = &As[srow * BK + scol];
    bf16_t* Bl = &Bs[srow * BK + scol];

    for (int seg = 0; seg < 3; ++seg) {
        const bf16_t* Ag = Aseg[seg] + (size_t)(bm * BM + srow) * DDIM + scol;
        const bf16_t* Bg = Bseg[seg] + (size_t)(bn * BN + srow) * DDIM + scol;
        for (int k0 = 0; k0 < DDIM; k0 += BK) {
            __syncthreads();  // previous iteration's LDS reads done
            async_cp16(Ag + k0, Al);
            async_cp16(Ag + (size_t)64 * DDIM + k0, Al + 64 * BK);
            async_cp16(Bg + k0, Bl);
            async_cp16(Bg + (size_t)64 * DDIM + k0, Bl + 64 * BK);
            __syncthreads();  // drains vmcnt before barrier -> LDS data visible

            bf16x8 af[4], bfr[4];
#pragma unroll
            for (int mi = 0; mi < 4; ++mi)
                af[mi] = *(const bf16x8*)&As[(wm + mi * 16 + m0) * BK + kq];
#pragma unroll
            for (int ni = 0; ni < 4; ++ni)
                bfr[ni] = *(const bf16x8*)&Bs[(wn + ni * 16 + m0) * BK + kq];
#pragma unroll
            for (int mi = 0; mi < 4; ++mi)
#pragma unroll
                for (int ni = 0; ni < 4; ++ni)
                    acc[mi][ni] = __builtin_amdgcn_mfma_f32_16x16x32_bf16(
                        af[mi], bfr[ni], acc[mi][ni], 0, 0, 0);
        }
    }

    // epilogue. C/D layout: col = lane&15, row = (lane>>4)*4 + reg  [m89/m91]
    const int ccol = lane & 15;
    const int crow = (lane >> 4) * 4;
#pragma unroll
    for (int mi = 0; mi < 4; ++mi) {
#pragma unroll
        for (int ni = 0; ni < 4; ++ni) {
#pragma unroll
            for (int r = 0; r < 4; ++r) {
                const int i = bm * BM + wm + mi * 16 + crow + r;
                const int j = bn * BN + wn + ni * 16 + ccol;
                const float v = acc[mi][ni][r];
                if (EPI == 1) {
                    Cf[(size_t)i * ldc + j] = 1.0f / (1.0f + __expf(-v));
                } else {
                    bf16_t h = (bf16_t)v;
                    bf16_t lo = (bf16_t)(v - (float)h);
                    Chi[(size_t)i * ldc + j] = h;
                    Clo[(size_t)i * ldc + j] = lo;
                }
            }
        }
    }
}

extern "C" void kernel_launch(void* const* d_in, const int* in_sizes, int n_in,
                              void* d_out, int out_size, void* d_ws, size_t ws_size,
                              hipStream_t stream) {
    const float* x  = (const float*)d_in[0];
    const float* y  = (const float*)d_in[1];
    const float* mx = (const float*)d_in[2];
    const float* my = (const float*)d_in[3];
    const float* W  = (const float*)d_in[4];
    float* out = (float*)d_out;

    const size_t ND = (size_t)N_ROWS * DDIM;  // 4,194,304
    const size_t WD = (size_t)DDIM * DDIM;    // 262,144

    bf16_t* ws = (bf16_t*)d_ws;
    bf16_t* xd_hi = ws;
    bf16_t* xd_lo = ws + ND;
    bf16_t* yd_hi = ws + 2 * ND;
    bf16_t* yd_lo = ws + 3 * ND;
    bf16_t* xt_hi = ws + 4 * ND;
    bf16_t* xt_lo = ws + 5 * ND;
    bf16_t* W_hi  = ws + 6 * ND;
    bf16_t* W_lo  = ws + 6 * ND + WD;
    // total: 6*ND + 2*WD elems = ~51.4 MB of ws

    // prep: dropout + split
    prep_split<<<(int)(ND / 4 / 256), 256, 0, stream>>>(x, mx, xd_hi, xd_lo, (int)(ND / 4));
    prep_split<<<(int)(ND / 4 / 256), 256, 0, stream>>>(y, my, yd_hi, yd_lo, (int)(ND / 4));
    prep_split<<<(int)(WD / 4 / 256), 256, 0, stream>>>(W, nullptr, W_hi, W_lo, (int)(WD / 4));

    // GEMM1: xt[n,k] = sum_d xd[n,d] * W[k,d]   (8192 x 512), split epilogue
    gemm_bt<0><<<dim3(DDIM / BN, N_ROWS / BM), 256, 0, stream>>>(
        xd_hi, xd_lo, W_hi, W_lo, nullptr, xt_hi, xt_lo, DDIM);

    // GEMM2: out[n,m] = sigmoid(sum_k xt[n,k] * yd[m,k])   (8192 x 8192)
    gemm_bt<1><<<dim3(M_ROWS / BN, N_ROWS / BM), 256, 0, stream>>>(
        xt_hi, xt_lo, yd_hi, yd_lo, out, nullptr, nullptr, M_ROWS);
}